// Round 1
// baseline (942.476 us; speedup 1.0000x reference)
//
#include <hip/hip_runtime.h>

#define LN_EPS 1e-5f

__global__ void deg_init_k(float* deg, int n) {
    int i = blockIdx.x * blockDim.x + threadIdx.x;
    if (i < n) deg[i] = 1.0f;  // self-loop
}

__global__ void deg_count_k(const int* __restrict__ dst, float* deg, int nE) {
    int e = blockIdx.x * blockDim.x + threadIdx.x;
    if (e < nE) atomicAdd(&deg[dst[e]], 1.0f);
}

__global__ void deg_rsqrt_k(float* deg, int n) {
    int i = blockIdx.x * blockDim.x + threadIdx.x;
    if (i < n) deg[i] = rsqrtf(deg[i]);
}

// Y[n,128] = X[n,128] @ W[128,128]; block = 256 threads handles 16 rows.
// Thread (c = tid&127, rbase = tid>>7) accumulates 8 rows in registers;
// W read coalesced from global (64KB, L1/L2 resident), X tile in LDS (8KB).
__global__ __launch_bounds__(256) void gemm128_k(const float* __restrict__ X,
                                                 const float* __restrict__ W,
                                                 float* __restrict__ Y, int n) {
    __shared__ float Xs[16 * 128];
    int tid = threadIdx.x;
    int row0 = blockIdx.x * 16;
    int nrows = min(16, n - row0);
    const float4* X4 = (const float4*)(X + (size_t)row0 * 128);
    float4* Xs4 = (float4*)Xs;
    for (int i = tid; i < nrows * 32; i += 256) Xs4[i] = X4[i];
    __syncthreads();
    int c = tid & 127;
    int rbase = tid >> 7;  // 0 or 1
    float acc[8] = {0.f, 0.f, 0.f, 0.f, 0.f, 0.f, 0.f, 0.f};
    for (int k = 0; k < 128; ++k) {
        float w = W[k * 128 + c];
#pragma unroll
        for (int rr = 0; rr < 8; ++rr)
            acc[rr] += Xs[(rbase + 2 * rr) * 128 + k] * w;
    }
#pragma unroll
    for (int rr = 0; rr < 8; ++rr) {
        int r = rbase + 2 * rr;
        if (r < nrows) Y[(size_t)(row0 + r) * 128 + c] = acc[rr];
    }
}

// out[i] = dinv[i]^2 * H[i]  (self-loop term init)
__global__ void self_init_k(const float* __restrict__ H,
                            const float* __restrict__ dinv,
                            float* __restrict__ out, int total) {
    int idx = blockIdx.x * blockDim.x + threadIdx.x;
    if (idx < total) {
        float di = dinv[idx >> 7];
        out[idx] = di * di * H[idx];
    }
}

// For each edge e (s->t), each of 128 threads handles one feature dim:
// out[t*128+d] += dinv[s]*dinv[t] * H[s*128+d]
__global__ void edge_agg_k(const int* __restrict__ src, const int* __restrict__ dst,
                           const float* __restrict__ dinv,
                           const float* __restrict__ H,
                           float* __restrict__ out, int nE) {
    int idx = blockIdx.x * blockDim.x + threadIdx.x;
    int e = idx >> 7;
    if (e >= nE) return;
    int d = idx & 127;
    int s = src[e];
    int t = dst[e];
    float norm = dinv[s] * dinv[t];
    atomicAdd(&out[t * 128 + d], norm * H[s * 128 + d]);
}

// One 64-lane wave per node: out = relu(LN(H + bias) * g + beta)
__global__ __launch_bounds__(256) void ln_relu_k(const float* __restrict__ H,
                                                 const float* __restrict__ bias,
                                                 const float* __restrict__ g,
                                                 const float* __restrict__ beta,
                                                 float* __restrict__ out, int n) {
    int wave = (blockIdx.x * blockDim.x + threadIdx.x) >> 6;
    int lane = threadIdx.x & 63;
    if (wave >= n) return;
    const float2* h2 = (const float2*)(H + (size_t)wave * 128);
    float2 v = h2[lane];
    v.x += bias[2 * lane];
    v.y += bias[2 * lane + 1];
    float sum = v.x + v.y;
#pragma unroll
    for (int off = 32; off > 0; off >>= 1) sum += __shfl_down(sum, off);
    sum = __shfl(sum, 0);
    float mu = sum * (1.0f / 128.0f);
    float dx = v.x - mu, dy = v.y - mu;
    float vs = dx * dx + dy * dy;
#pragma unroll
    for (int off = 32; off > 0; off >>= 1) vs += __shfl_down(vs, off);
    vs = __shfl(vs, 0);
    float rstd = rsqrtf(vs * (1.0f / 128.0f) + LN_EPS);
    float o0 = fmaxf(dx * rstd * g[2 * lane] + beta[2 * lane], 0.0f);
    float o1 = fmaxf(dy * rstd * g[2 * lane + 1] + beta[2 * lane + 1], 0.0f);
    ((float2*)(out + (size_t)wave * 128))[lane] = make_float2(o0, o1);
}

extern "C" void kernel_launch(void* const* d_in, const int* in_sizes, int n_in,
                              void* d_out, int out_size, void* d_ws, size_t ws_size,
                              hipStream_t stream) {
    const float* x   = (const float*)d_in[0];
    const int*   ei  = (const int*)d_in[1];
    const float* W1  = (const float*)d_in[2];
    const float* b1  = (const float*)d_in[3];
    const float* g1  = (const float*)d_in[4];
    const float* be1 = (const float*)d_in[5];
    const float* W2  = (const float*)d_in[6];
    const float* b2  = (const float*)d_in[7];
    const float* g2  = (const float*)d_in[8];
    const float* be2 = (const float*)d_in[9];
    float* out = (float*)d_out;

    int n  = in_sizes[0] / 128;   // 50000
    int nE = in_sizes[1] / 2;     // 800000
    const int* src = ei;
    const int* dst = ei + nE;

    char* ws = (char*)d_ws;
    float* dinv = (float*)ws;                                    // n floats
    float* bufA = (float*)(ws + (1 << 19));                      // n*128 floats
    float* bufB = (float*)(ws + (1 << 19) + (size_t)n * 128 * 4);

    int total = n * 128;
    dim3 blk(256);

    // degree -> dinv
    deg_init_k<<<(n + 255) / 256, blk, 0, stream>>>(dinv, n);
    deg_count_k<<<(nE + 255) / 256, blk, 0, stream>>>(dst, dinv, nE);
    deg_rsqrt_k<<<(n + 255) / 256, blk, 0, stream>>>(dinv, n);

    // layer 1
    gemm128_k<<<(n + 15) / 16, blk, 0, stream>>>(x, W1, bufA, n);
    self_init_k<<<(total + 255) / 256, blk, 0, stream>>>(bufA, dinv, bufB, total);
    edge_agg_k<<<((size_t)nE * 128 + 255) / 256, blk, 0, stream>>>(src, dst, dinv, bufA, bufB, nE);
    ln_relu_k<<<(n + 3) / 4, blk, 0, stream>>>(bufB, b1, g1, be1, bufA, n);

    // layer 2
    gemm128_k<<<(n + 15) / 16, blk, 0, stream>>>(bufA, W2, bufB, n);
    self_init_k<<<(total + 255) / 256, blk, 0, stream>>>(bufB, dinv, bufA, total);
    edge_agg_k<<<((size_t)nE * 128 + 255) / 256, blk, 0, stream>>>(src, dst, dinv, bufB, bufA, nE);
    ln_relu_k<<<(n + 3) / 4, blk, 0, stream>>>(bufA, b2, g2, be2, out, n);
}

// Round 2
// 386.043 us; speedup vs baseline: 2.4414x; 2.4414x over previous
//
#include <hip/hip_runtime.h>

#define LN_EPS 1e-5f

// ---------- degree / CSR build ----------
__global__ void zero_counts_k(int* counts, int n) {
    int i = blockIdx.x * blockDim.x + threadIdx.x;
    if (i < n) counts[i] = 0;
}

__global__ void count_k(const int* __restrict__ dst, int* counts, int nE) {
    int e = blockIdx.x * blockDim.x + threadIdx.x;
    if (e < nE) atomicAdd(&counts[dst[e]], 1);
}

__global__ void dinv_k(const int* __restrict__ counts, float* dinv, int n) {
    int i = blockIdx.x * blockDim.x + threadIdx.x;
    if (i < n) dinv[i] = rsqrtf((float)(counts[i] + 1));  // +1 self-loop
}

// inclusive block scan of counts -> incl, block totals -> bsums
__global__ __launch_bounds__(256) void scan1_k(const int* __restrict__ counts,
                                               int* __restrict__ incl,
                                               int* __restrict__ bsums, int n) {
    __shared__ int s[256];
    int i = blockIdx.x * 256 + threadIdx.x;
    int v = (i < n) ? counts[i] : 0;
    s[threadIdx.x] = v;
    __syncthreads();
    for (int off = 1; off < 256; off <<= 1) {
        int t = (threadIdx.x >= off) ? s[threadIdx.x - off] : 0;
        __syncthreads();
        s[threadIdx.x] += t;
        __syncthreads();
    }
    if (i < n) incl[i] = s[threadIdx.x];
    if (threadIdx.x == 255) bsums[blockIdx.x] = s[255];
}

// exclusive scan of bsums in place (nb <= 256)
__global__ __launch_bounds__(256) void scan2_k(int* bsums, int nb) {
    __shared__ int s[256];
    int v = (threadIdx.x < nb) ? bsums[threadIdx.x] : 0;
    s[threadIdx.x] = v;
    __syncthreads();
    for (int off = 1; off < 256; off <<= 1) {
        int t = (threadIdx.x >= off) ? s[threadIdx.x - off] : 0;
        __syncthreads();
        s[threadIdx.x] += t;
        __syncthreads();
    }
    if (threadIdx.x < nb) bsums[threadIdx.x] = s[threadIdx.x] - v;
}

__global__ __launch_bounds__(256) void scan3_k(const int* __restrict__ counts,
                                               const int* __restrict__ incl,
                                               const int* __restrict__ bsums,
                                               int* __restrict__ rowptr,
                                               int* __restrict__ cursor, int n, int nE) {
    int i = blockIdx.x * 256 + threadIdx.x;
    if (i < n) {
        int ex = incl[i] - counts[i] + bsums[blockIdx.x];
        rowptr[i] = ex;
        cursor[i] = ex;
    }
    if (i == n) rowptr[n] = nE;
}

__global__ void scatter_k(const int* __restrict__ src, const int* __restrict__ dst,
                          int* cursor, int* __restrict__ eidx, int nE) {
    int e = blockIdx.x * blockDim.x + threadIdx.x;
    if (e < nE) {
        int pos = atomicAdd(&cursor[dst[e]], 1);
        eidx[pos] = src[e];
    }
}

// ---------- GEMM: Y[r,:] = dinv[r] * (X[r,:] @ W) ----------
__global__ __launch_bounds__(256) void gemm128_k(const float* __restrict__ X,
                                                 const float* __restrict__ W,
                                                 const float* __restrict__ dinv,
                                                 float* __restrict__ Y, int n) {
    __shared__ float Xs[16 * 128];
    int tid = threadIdx.x;
    int row0 = blockIdx.x * 16;
    int nrows = min(16, n - row0);
    const float4* X4 = (const float4*)(X + (size_t)row0 * 128);
    float4* Xs4 = (float4*)Xs;
    for (int i = tid; i < nrows * 32; i += 256) Xs4[i] = X4[i];
    __syncthreads();
    int c = tid & 127;
    int rbase = tid >> 7;  // 0 or 1
    float acc[8] = {0.f, 0.f, 0.f, 0.f, 0.f, 0.f, 0.f, 0.f};
    for (int k = 0; k < 128; ++k) {
        float w = W[k * 128 + c];
#pragma unroll
        for (int rr = 0; rr < 8; ++rr)
            acc[rr] += Xs[(rbase + 2 * rr) * 128 + k] * w;
    }
#pragma unroll
    for (int rr = 0; rr < 8; ++rr) {
        int r = rbase + 2 * rr;
        if (r < nrows) Y[(size_t)(row0 + r) * 128 + c] = acc[rr] * dinv[row0 + r];
    }
}

// ---------- fused gather-aggregate + bias + LN + ReLU ----------
// One 64-lane wave per node. Hs is already scaled by dinv[src].
// out[t] = relu(LN(dinv[t]*(Hs[t] + sum_{s in N(t)} Hs[s]) + bias) * g + beta)
__global__ __launch_bounds__(256) void agg_ln_k(const float* __restrict__ Hs,
                                                const float* __restrict__ dinv,
                                                const int* __restrict__ rowptr,
                                                const int* __restrict__ eidx,
                                                const float* __restrict__ bias,
                                                const float* __restrict__ g,
                                                const float* __restrict__ beta,
                                                float* __restrict__ out, int n) {
    int wave = (blockIdx.x * blockDim.x + threadIdx.x) >> 6;
    int lane = threadIdx.x & 63;
    if (wave >= n) return;
    const float2* H2 = (const float2*)Hs;
    float2 acc = H2[(size_t)wave * 64 + lane];  // self-loop term (dinv folded in)
    int beg = rowptr[wave];
    int end = rowptr[wave + 1];
    int e = beg;
    // unroll-by-2 to get two gathers in flight
    for (; e + 1 < end; e += 2) {
        int s0 = eidx[e];
        int s1 = eidx[e + 1];
        float2 v0 = H2[(size_t)s0 * 64 + lane];
        float2 v1 = H2[(size_t)s1 * 64 + lane];
        acc.x += v0.x + v1.x;
        acc.y += v0.y + v1.y;
    }
    if (e < end) {
        int s0 = eidx[e];
        float2 v0 = H2[(size_t)s0 * 64 + lane];
        acc.x += v0.x;
        acc.y += v0.y;
    }
    float dt = dinv[wave];
    float vx = acc.x * dt + bias[2 * lane];
    float vy = acc.y * dt + bias[2 * lane + 1];
    float sum = vx + vy;
#pragma unroll
    for (int off = 32; off > 0; off >>= 1) sum += __shfl_down(sum, off);
    sum = __shfl(sum, 0);
    float mu = sum * (1.0f / 128.0f);
    float dx = vx - mu, dy = vy - mu;
    float vs = dx * dx + dy * dy;
#pragma unroll
    for (int off = 32; off > 0; off >>= 1) vs += __shfl_down(vs, off);
    vs = __shfl(vs, 0);
    float rstd = rsqrtf(vs * (1.0f / 128.0f) + LN_EPS);
    float o0 = fmaxf(dx * rstd * g[2 * lane] + beta[2 * lane], 0.0f);
    float o1 = fmaxf(dy * rstd * g[2 * lane + 1] + beta[2 * lane + 1], 0.0f);
    ((float2*)(out + (size_t)wave * 128))[lane] = make_float2(o0, o1);
}

extern "C" void kernel_launch(void* const* d_in, const int* in_sizes, int n_in,
                              void* d_out, int out_size, void* d_ws, size_t ws_size,
                              hipStream_t stream) {
    const float* x   = (const float*)d_in[0];
    const int*   ei  = (const int*)d_in[1];
    const float* W1  = (const float*)d_in[2];
    const float* b1  = (const float*)d_in[3];
    const float* g1  = (const float*)d_in[4];
    const float* be1 = (const float*)d_in[5];
    const float* W2  = (const float*)d_in[6];
    const float* b2  = (const float*)d_in[7];
    const float* g2  = (const float*)d_in[8];
    const float* be2 = (const float*)d_in[9];
    float* out = (float*)d_out;

    int n  = in_sizes[0] / 128;   // 50000
    int nE = in_sizes[1] / 2;     // 800000
    const int* src = ei;
    const int* dst = ei + nE;

    // workspace carve-up (256B aligned)
    char* p = (char*)d_ws;
    auto carve = [&](size_t bytes) {
        char* r = p;
        p += (bytes + 255) & ~(size_t)255;
        return r;
    };
    float* dinv   = (float*)carve((size_t)n * 4);
    int*   counts = (int*)carve((size_t)n * 4);
    int*   incl   = (int*)carve((size_t)n * 4);
    int*   bsums  = (int*)carve(256 * 4);
    int*   rowptr = (int*)carve((size_t)(n + 1) * 4);
    int*   cursor = (int*)carve((size_t)n * 4);
    int*   eidx   = (int*)carve((size_t)nE * 4);
    float* bufA   = (float*)carve((size_t)n * 128 * 4);
    float* bufB   = (float*)carve((size_t)n * 128 * 4);

    dim3 blk(256);
    int nb_n  = (n + 255) / 256;
    int nb_e  = (nE + 255) / 256;

    // CSR build
    zero_counts_k<<<nb_n, blk, 0, stream>>>(counts, n);
    count_k<<<nb_e, blk, 0, stream>>>(dst, counts, nE);
    dinv_k<<<nb_n, blk, 0, stream>>>(counts, dinv, n);
    scan1_k<<<nb_n, blk, 0, stream>>>(counts, incl, bsums, n);
    scan2_k<<<1, blk, 0, stream>>>(bsums, nb_n);
    scan3_k<<<(n + 256) / 256, blk, 0, stream>>>(counts, incl, bsums, rowptr, cursor, n, nE);
    scatter_k<<<nb_e, blk, 0, stream>>>(src, dst, cursor, eidx, nE);

    int nwave_blocks = (n + 3) / 4;  // 4 waves per 256-thread block

    // layer 1
    gemm128_k<<<(n + 15) / 16, blk, 0, stream>>>(x, W1, dinv, bufA, n);
    agg_ln_k<<<nwave_blocks, blk, 0, stream>>>(bufA, dinv, rowptr, eidx, b1, g1, be1, bufB, n);

    // layer 2
    gemm128_k<<<(n + 15) / 16, blk, 0, stream>>>(bufB, W2, dinv, bufA, n);
    agg_ln_k<<<nwave_blocks, blk, 0, stream>>>(bufA, dinv, rowptr, eidx, b2, g2, be2, out, n);
}

// Round 3
// 299.521 us; speedup vs baseline: 3.1466x; 1.2889x over previous
//
#include <hip/hip_runtime.h>

#define LN_EPS 1e-5f

typedef __attribute__((ext_vector_type(8))) short bf16x8;
typedef __attribute__((ext_vector_type(4))) float f32x4;

__device__ __forceinline__ unsigned short f2bf(float f) {
    union { float f; unsigned u; } x; x.f = f;
    unsigned r = (x.u + 0x7FFFu + ((x.u >> 16) & 1u)) >> 16;
    return (unsigned short)r;
}
__device__ __forceinline__ float bfbits2f(unsigned hi) {  // hi = bf16 bits already in [31:16]
    union { unsigned u; float f; } x; x.u = hi; return x.f;
}

// ---------- degree / CSR build ----------
__global__ void zero_counts_k(int* counts, int n) {
    int i = blockIdx.x * blockDim.x + threadIdx.x;
    if (i < n) counts[i] = 0;
}

__global__ void count_k(const int* __restrict__ dst, int* counts, int nE) {
    int e = blockIdx.x * blockDim.x + threadIdx.x;
    if (e < nE) atomicAdd(&counts[dst[e]], 1);
}

__global__ __launch_bounds__(256) void scan1_k(const int* __restrict__ counts,
                                               int* __restrict__ incl,
                                               int* __restrict__ bsums, int n) {
    __shared__ int s[256];
    int i = blockIdx.x * 256 + threadIdx.x;
    int v = (i < n) ? counts[i] : 0;
    s[threadIdx.x] = v;
    __syncthreads();
    for (int off = 1; off < 256; off <<= 1) {
        int t = (threadIdx.x >= off) ? s[threadIdx.x - off] : 0;
        __syncthreads();
        s[threadIdx.x] += t;
        __syncthreads();
    }
    if (i < n) incl[i] = s[threadIdx.x];
    if (threadIdx.x == 255) bsums[blockIdx.x] = s[255];
}

__global__ __launch_bounds__(256) void scan2_k(int* bsums, int nb) {
    __shared__ int s[256];
    int v = (threadIdx.x < nb) ? bsums[threadIdx.x] : 0;
    s[threadIdx.x] = v;
    __syncthreads();
    for (int off = 1; off < 256; off <<= 1) {
        int t = (threadIdx.x >= off) ? s[threadIdx.x - off] : 0;
        __syncthreads();
        s[threadIdx.x] += t;
        __syncthreads();
    }
    if (threadIdx.x < nb) bsums[threadIdx.x] = s[threadIdx.x] - v;
}

__global__ __launch_bounds__(256) void scan3_k(const int* __restrict__ counts,
                                               const int* __restrict__ incl,
                                               const int* __restrict__ bsums,
                                               int* __restrict__ rowptr,
                                               int* __restrict__ cursor,
                                               float* __restrict__ dinv, int n, int nE) {
    int i = blockIdx.x * 256 + threadIdx.x;
    if (i < n) {
        int ex = incl[i] - counts[i] + bsums[blockIdx.x];
        rowptr[i] = ex;
        cursor[i] = ex;
        dinv[i] = rsqrtf((float)(counts[i] + 1));
    }
    if (i == n) rowptr[n] = nE;
}

__global__ void scatter_k(const int* __restrict__ src, const int* __restrict__ dst,
                          int* cursor, int* __restrict__ eidx, int nE) {
    int e = blockIdx.x * blockDim.x + threadIdx.x;
    if (e < nE) {
        int pos = atomicAdd(&cursor[dst[e]], 1);
        eidx[pos] = src[e];
    }
}

// ---------- conversions / packing ----------
// X fp32 -> bf16, padded rows zeroed
__global__ void convx_k(const float* __restrict__ X, unsigned short* __restrict__ Xb,
                        int total, int total_pad) {
    int i = blockIdx.x * blockDim.x + threadIdx.x;
    if (i < total_pad) Xb[i] = (i < total) ? f2bf(X[i]) : (unsigned short)0;
}

// Pack both W1 and W2 into B-fragment-contiguous bf16 layout:
// Wp[(((kc*128 + col)*4 + kb)*8) + j] = W[(kc*32 + kb*8 + j)*128 + col]
__global__ void packw_k(const float* __restrict__ W1, const float* __restrict__ W2,
                        unsigned short* __restrict__ Wp1, unsigned short* __restrict__ Wp2) {
    int idx = blockIdx.x * blockDim.x + threadIdx.x;  // 0..32767
    const float* W = (idx < 16384) ? W1 : W2;
    unsigned short* Wp = (idx < 16384) ? Wp1 : Wp2;
    int t = idx & 16383;
    int k = t >> 7, col = t & 127;
    int kc = k >> 5, kr = k & 31, kb = kr >> 3, j = kr & 7;
    Wp[(((kc * 128 + col) * 4 + kb) * 8) + j] = f2bf(W[k * 128 + col]);
}

// ---------- MFMA GEMM: Y[r,:] = bf16( dinv[r] * (Xb[r,:] @ W) ) ----------
// Block: 256 thr = 4 waves; block tile 64 rows x 128 cols.
// Wave (rgrp = wid&1, cgrp = wid>>1): 32 rows x 64 cols = 2 A-frags x 4 B-frags.
__global__ __launch_bounds__(256) void mfma_gemm_k(const unsigned short* __restrict__ Xb,
                                                   const unsigned short* __restrict__ Wp,
                                                   const float* __restrict__ dinv,
                                                   unsigned short* __restrict__ Y, int n) {
    int wid = threadIdx.x >> 6;
    int lane = threadIdx.x & 63;
    int rgrp = wid & 1;
    int cgrp = wid >> 1;
    int row0 = blockIdx.x * 64 + rgrp * 32;
    int m = lane & 15;
    int kb = lane >> 4;  // 0..3

    f32x4 acc[2][4] = {};
#pragma unroll
    for (int kc = 0; kc < 4; ++kc) {
        bf16x8 a[2], b[4];
#pragma unroll
        for (int rs = 0; rs < 2; ++rs) {
            int r = row0 + rs * 16 + m;
            a[rs] = *(const bf16x8*)(Xb + (size_t)r * 128 + kc * 32 + kb * 8);
        }
#pragma unroll
        for (int cf = 0; cf < 4; ++cf) {
            int col = cgrp * 64 + cf * 16 + m;
            b[cf] = *(const bf16x8*)(Wp + (((kc * 128 + col) * 4 + kb) * 8));
        }
#pragma unroll
        for (int rs = 0; rs < 2; ++rs)
#pragma unroll
            for (int cf = 0; cf < 4; ++cf)
                acc[rs][cf] = __builtin_amdgcn_mfma_f32_16x16x32_bf16(a[rs], b[cf], acc[rs][cf], 0, 0, 0);
    }
    // D layout: row = (lane>>4)*4 + reg, col = lane&15
#pragma unroll
    for (int rs = 0; rs < 2; ++rs) {
        int rbase = row0 + rs * 16 + kb * 4;
#pragma unroll
        for (int r = 0; r < 4; ++r) {
            int row = rbase + r;
            if (row >= n) continue;
            float dv = dinv[row];
#pragma unroll
            for (int cf = 0; cf < 4; ++cf) {
                int col = cgrp * 64 + cf * 16 + m;
                Y[(size_t)row * 128 + col] = f2bf(acc[rs][cf][r] * dv);
            }
        }
    }
}

// ---------- fused gather-aggregate + bias + LN + ReLU ----------
// One wave per node; Hs is bf16 (dinv[src] folded in). Lane holds dims {2*lane, 2*lane+1}.
template <bool OUT_BF16>
__global__ __launch_bounds__(256) void agg_ln_k(const unsigned short* __restrict__ Hs,
                                                const float* __restrict__ dinv,
                                                const int* __restrict__ rowptr,
                                                const int* __restrict__ eidx,
                                                const float* __restrict__ bias,
                                                const float* __restrict__ g,
                                                const float* __restrict__ beta,
                                                void* __restrict__ out, int n) {
    int wave = (blockIdx.x * blockDim.x + threadIdx.x) >> 6;
    int lane = threadIdx.x & 63;
    if (wave >= n) return;
    const unsigned* H4 = (const unsigned*)Hs;  // one uint = 2 bf16
    unsigned v0 = H4[(size_t)wave * 64 + lane];
    float ax = bfbits2f(v0 << 16);
    float ay = bfbits2f(v0 & 0xFFFF0000u);
    int beg = rowptr[wave];
    int end = rowptr[wave + 1];
    int e = beg;
    for (; e + 3 < end; e += 4) {
        int s0 = eidx[e], s1 = eidx[e + 1], s2 = eidx[e + 2], s3 = eidx[e + 3];
        unsigned u0 = H4[(size_t)s0 * 64 + lane];
        unsigned u1 = H4[(size_t)s1 * 64 + lane];
        unsigned u2 = H4[(size_t)s2 * 64 + lane];
        unsigned u3 = H4[(size_t)s3 * 64 + lane];
        ax += bfbits2f(u0 << 16) + bfbits2f(u1 << 16) + bfbits2f(u2 << 16) + bfbits2f(u3 << 16);
        ay += bfbits2f(u0 & 0xFFFF0000u) + bfbits2f(u1 & 0xFFFF0000u) +
              bfbits2f(u2 & 0xFFFF0000u) + bfbits2f(u3 & 0xFFFF0000u);
    }
    for (; e < end; ++e) {
        unsigned u0 = H4[(size_t)eidx[e] * 64 + lane];
        ax += bfbits2f(u0 << 16);
        ay += bfbits2f(u0 & 0xFFFF0000u);
    }
    float dt = dinv[wave];
    float vx = ax * dt + bias[2 * lane];
    float vy = ay * dt + bias[2 * lane + 1];
    float sum = vx + vy;
#pragma unroll
    for (int off = 32; off > 0; off >>= 1) sum += __shfl_down(sum, off);
    sum = __shfl(sum, 0);
    float mu = sum * (1.0f / 128.0f);
    float dx = vx - mu, dy = vy - mu;
    float vs = dx * dx + dy * dy;
#pragma unroll
    for (int off = 32; off > 0; off >>= 1) vs += __shfl_down(vs, off);
    vs = __shfl(vs, 0);
    float rstd = rsqrtf(vs * (1.0f / 128.0f) + LN_EPS);
    float o0 = fmaxf(dx * rstd * g[2 * lane] + beta[2 * lane], 0.0f);
    float o1 = fmaxf(dy * rstd * g[2 * lane + 1] + beta[2 * lane + 1], 0.0f);
    if (OUT_BF16) {
        unsigned pack = (unsigned)f2bf(o0) | ((unsigned)f2bf(o1) << 16);
        ((unsigned*)out)[(size_t)wave * 64 + lane] = pack;
    } else {
        ((float2*)out)[(size_t)wave * 64 + lane] = make_float2(o0, o1);
    }
}

extern "C" void kernel_launch(void* const* d_in, const int* in_sizes, int n_in,
                              void* d_out, int out_size, void* d_ws, size_t ws_size,
                              hipStream_t stream) {
    const float* x   = (const float*)d_in[0];
    const int*   ei  = (const int*)d_in[1];
    const float* W1  = (const float*)d_in[2];
    const float* b1  = (const float*)d_in[3];
    const float* g1  = (const float*)d_in[4];
    const float* be1 = (const float*)d_in[5];
    const float* W2  = (const float*)d_in[6];
    const float* b2  = (const float*)d_in[7];
    const float* g2  = (const float*)d_in[8];
    const float* be2 = (const float*)d_in[9];
    float* out = (float*)d_out;

    int n  = in_sizes[0] / 128;   // 50000
    int nE = in_sizes[1] / 2;     // 800000
    const int* src = ei;
    const int* dst = ei + nE;

    int nblk64 = (n + 63) / 64;       // GEMM blocks
    int npad   = nblk64 * 64;         // padded rows for OOB-safe frag loads

    char* p = (char*)d_ws;
    auto carve = [&](size_t bytes) {
        char* r = p;
        p += (bytes + 255) & ~(size_t)255;
        return r;
    };
    float* dinv   = (float*)carve((size_t)n * 4);
    int*   counts = (int*)carve((size_t)n * 4);
    int*   incl   = (int*)carve((size_t)n * 4);
    int*   bsums  = (int*)carve(256 * 4);
    int*   rowptr = (int*)carve((size_t)(n + 1) * 4);
    int*   cursor = (int*)carve((size_t)n * 4);
    int*   eidx   = (int*)carve((size_t)nE * 4);
    unsigned short* Wp1 = (unsigned short*)carve(16384 * 2);
    unsigned short* Wp2 = (unsigned short*)carve(16384 * 2);
    unsigned short* Xb  = (unsigned short*)carve((size_t)npad * 128 * 2);  // bf16 layer input
    unsigned short* Hs  = (unsigned short*)carve((size_t)npad * 128 * 2);  // bf16 scaled GEMM out
    unsigned short* Hb  = (unsigned short*)carve((size_t)npad * 128 * 2);  // bf16 layer-1 result

    dim3 blk(256);
    int nb_n = (n + 255) / 256;
    int nb_e = (nE + 255) / 256;
    int total = n * 128, total_pad = npad * 128;

    // CSR build + dinv
    zero_counts_k<<<nb_n, blk, 0, stream>>>(counts, n);
    count_k<<<nb_e, blk, 0, stream>>>(dst, counts, nE);
    scan1_k<<<nb_n, blk, 0, stream>>>(counts, incl, bsums, n);
    scan2_k<<<1, blk, 0, stream>>>(bsums, nb_n);
    scan3_k<<<(n + 256) / 256, blk, 0, stream>>>(counts, incl, bsums, rowptr, cursor, dinv, n, nE);
    scatter_k<<<nb_e, blk, 0, stream>>>(src, dst, cursor, eidx, nE);

    // conversions
    convx_k<<<(total_pad + 255) / 256, blk, 0, stream>>>(x, Xb, total, total_pad);
    packw_k<<<32768 / 256, blk, 0, stream>>>(W1, W2, Wp1, Wp2);

    int nwave_blocks = (n + 3) / 4;

    // layer 1
    mfma_gemm_k<<<nblk64, blk, 0, stream>>>(Xb, Wp1, dinv, Hs, n);
    agg_ln_k<true><<<nwave_blocks, blk, 0, stream>>>(Hs, dinv, rowptr, eidx, b1, g1, be1, Hb, n);

    // layer 2 (Hb padding rows are finite garbage; OOB accum rows are discarded by store guard)
    mfma_gemm_k<<<nblk64, blk, 0, stream>>>(Hb, Wp2, dinv, Hs, n);
    agg_ln_k<false><<<nwave_blocks, blk, 0, stream>>>(Hs, dinv, rowptr, eidx, b2, g2, be2, out, n);
}